// Round 1
// baseline (540.552 us; speedup 1.0000x reference)
//
#include <hip/hip_runtime.h>

#define NEGF -1e30f
#define EPSF 1e-7f

// CTC forward (negative log-likelihood), blank = C-1, full label lengths.
// One block per batch element. Thread s owns extended state s (s=0..255);
// thread 255 additionally owns state 256 entirely in registers.
// All math in log2 domain (v_exp_f32/v_log_f32 are 2^x / log2 x); final
// loss scaled by ln2.
__global__ __launch_bounds__(256)
void ctc_fwd_kernel(const int* __restrict__ y_true,
                    const float* __restrict__ y_pred,
                    float* __restrict__ out,
                    int T, int C, int L) {
    const int b   = blockIdx.x;
    const int tid = threadIdx.x;

    __shared__ float row[4][256];    // 4-deep ring of probability rows
    __shared__ float alpha[2][264];  // [0..1]=NEG pad, state s at index s+2

    const float* Yb = y_pred + (size_t)b * T * C;
    const int*   lb = y_true + (size_t)b * L;

    // Extended label for state s=tid: odd -> label[(s-1)/2], even -> blank.
    const bool odd = (tid & 1) != 0;
    const int  lab = odd ? lb[tid >> 1] : (C - 1);
    // skip (s-2 transition) allowed iff ext[s]!=blank && ext[s]!=ext[s-2]
    const bool skip = odd && (tid >= 3) && (lab != lb[(tid >> 1) - 1]);

    if (tid < 2) { alpha[0][tid] = NEGF; alpha[1][tid] = NEGF; }

    // Row 0 + prefetch rows 1..3 (addresses static -> deep pipeline).
    float r0 = Yb[tid];
    float p0 = Yb[(size_t)1 * C + tid];
    float p1 = Yb[(size_t)2 * C + tid];
    float p2 = Yb[(size_t)3 * C + tid];
    row[0][tid] = r0;
    __syncthreads();

    // alpha_0: states 0 (blank) and 1 (first label) only.
    float a_self;
    if (tid == 0)      a_self = log2f(row[0][C - 1] + EPSF);
    else if (tid == 1) a_self = log2f(row[0][lab]   + EPSF);
    else               a_self = NEGF;
    float a_self2 = NEGF;  // state 256 (thread 255 only)
    alpha[0][tid + 2] = a_self;

    for (int t = 1; t < T; ++t) {
        const int rb = t & 3;
        row[rb][tid] = p0;                 // row t (loaded 3 iters ago)
        p0 = p1; p1 = p2;
        if (t + 3 < T) p2 = Yb[(size_t)(t + 3) * C + tid];
        __syncthreads();                   // row t + alpha[t-1] visible

        const float* ap = alpha[(t - 1) & 1];
        const float lp = log2f(row[rb][lab] + EPSF);
        const float a1 = a_self;           // stay
        const float a2 = ap[tid + 1];      // from s-1
        const float a3 = skip ? ap[tid] : NEGF;  // from s-2
        const float m  = fmaxf(a1, fmaxf(a2, a3));
        const float sum = exp2f(a1 - m) + exp2f(a2 - m) + exp2f(a3 - m);
        const float anew = m + log2f(sum) + lp;
        alpha[t & 1][tid + 2] = anew;

        if (tid == 255) {                  // state 256 (final blank)
            const float lpb = log2f(row[rb][C - 1] + EPSF);
            const float b1 = a_self2;      // stay
            const float b2 = a_self;       // from s-1 = old alpha[255]
            const float mb = fmaxf(b1, b2);
            a_self2 = mb + log2f(exp2f(b1 - mb) + exp2f(b2 - mb)) + lpb;
        }
        a_self = anew;
    }

    if (tid == 255) {
        // loss = -ln P = -ln2 * log2addexp(alpha_T[S-1], alpha_T[S-2])
        const float x = a_self2, y = a_self;
        const float m = fmaxf(x, y);
        out[b] = -0.69314718055994530942f *
                 (m + log2f(exp2f(x - m) + exp2f(y - m)));
    }
}

extern "C" void kernel_launch(void* const* d_in, const int* in_sizes, int n_in,
                              void* d_out, int out_size, void* d_ws, size_t ws_size,
                              hipStream_t stream) {
    const int*   y_true = (const int*)d_in[0];
    const float* y_pred = (const float*)d_in[1];
    float*       out    = (float*)d_out;

    const int B = out_size;                       // 512
    const int L = in_sizes[0] / B;                // 128
    const int C = 256;                            // channels (blank = C-1)
    const int T = in_sizes[1] / (B * C);          // 512

    ctc_fwd_kernel<<<B, 256, 0, stream>>>(y_true, y_pred, out, T, C, L);
}